// Round 4
// baseline (86.015 us; speedup 1.0000x reference)
//
#include <hip/hip_runtime.h>
#include <math.h>

// X[8192,64], Y[8192,64] fp32.
// d2[i][j] = x2_i + y2_j - 2<x_i,y_j>;  out = mean_i sqrt(min_j d2) + mean_j sqrt(min_i d2)
//
// R9: 2 kernels (prep folded into mine; cooperative launch from R8 failed —
// never executed under harness graph capture, out stayed 0). mine: 512 blocks
// (64 itiles x 8 slices) = 2 blocks/CU. Reads fp32 X/Y directly (4 MB total,
// L2-resident): A fragments converted to bf16(-2x) on the fly (exact: x2 is
// an exponent shift), block x2 computed cooperatively into LDS; Y slice
// streamed per chunk fp32->bf16 in the existing double-buffer prefetch slot,
// y2 computed per chunk via 8-lane shfl reduce into LDS. 16x16x32 bf16 MFMA
// with C init = x2_i + y2_j -> accumulator exits as d2; epilogue pure
// v_min3_f32. Row-half col partials combined via 2KB LDS -> cslab [64][8192].
// finish: sqrt + mean reductions. Harness d_ws 0xAA fill (~41us, 268MB) is
// inside the timed window and is a fixed floor we cannot affect.

#define NROWS 8192
#define DDIM  64
#define ITILES 64     // 8192 / 128 i-rows per block
#define SLICES 8      // j: 8 slices x 1024
#define CHUNKS 8      // 8 x 128 j per block
#define LSTR 72       // LDS row stride (bf16): 144 B -> 16B-aligned, 2-way-max banks

typedef __bf16 bf16_t;
typedef bf16_t bf16x8 __attribute__((ext_vector_type(8)));
typedef float  f32x4  __attribute__((ext_vector_type(4)));

__global__ __launch_bounds__(256, 2)
void mine_kernel(const float* __restrict__ X, const float* __restrict__ Y,
                 float* __restrict__ rslab, float* __restrict__ cslab,
                 float* __restrict__ out) {
  __shared__ bf16_t Ys[2][128 * LSTR];   // 2 x 18 KB
  __shared__ float y2L[2][128];          // per-chunk y2 (fp32), double-buffered
  __shared__ float x2s[128];             // block-local x2
  __shared__ float credL[2][2][128];     // [parity][rh][col] col-partial exchange

  const int tid = threadIdx.x;
  const int L = tid & 63;
  const int w = tid >> 6;
  const int lr = L & 15;
  const int q = L >> 4;
  const int rh = w >> 1;              // wave row-half
  const int ch = w & 1;               // wave col-half
  const int itile = blockIdx.x & (ITILES - 1);
  const int slice = blockIdx.x >> 6;  // 0..7
  const int i0 = itile * 128;
  const int rgb = rh * 64;
  const int cgb = ch * 64;
  const int jbase = slice * (CHUNKS * 128);   // slice * 1024

  if (blockIdx.x == 0 && tid == 0) out[0] = 0.f;

  // ---- x2 for this block's 128 rows (fp32, cooperative) ----
  {
    int r = tid >> 1, hh = tid & 1;   // 2 threads/row, 32 elems each
    const float4* xp = (const float4*)(X + (i0 + r) * DDIM + hh * 32);
    float s = 0.f;
#pragma unroll
    for (int k = 0; k < 8; ++k) {
      float4 v = xp[k];
      s = fmaf(v.x, v.x, s); s = fmaf(v.y, v.y, s);
      s = fmaf(v.z, v.z, s); s = fmaf(v.w, v.w, s);
    }
    s += __shfl_xor(s, 1, 64);
    if (hh == 0) x2s[r] = s;
  }

  // ---- A fragments from fp32 X, scaled by -2 (exact in bf16) ----
  bf16x8 Af[8];
#pragma unroll
  for (int a = 0; a < 4; ++a) {
    int row = i0 + rgb + a * 16 + lr;
#pragma unroll
    for (int h = 0; h < 2; ++h) {
      const float4* xp = (const float4*)(X + row * DDIM + h * 32 + q * 8);
      float4 u0 = xp[0], u1 = xp[1];
      Af[a * 2 + h] = (bf16x8){
          (bf16_t)(-2.f * u0.x), (bf16_t)(-2.f * u0.y),
          (bf16_t)(-2.f * u0.z), (bf16_t)(-2.f * u0.w),
          (bf16_t)(-2.f * u1.x), (bf16_t)(-2.f * u1.y),
          (bf16_t)(-2.f * u1.z), (bf16_t)(-2.f * u1.w)};
    }
  }

  // ---- prologue: stage chunk 0 (fp32 -> bf16 into LDS + y2 reduce) ----
#pragma unroll
  for (int p = 0; p < 4; ++p) {
    int f = p * 256 + tid;
    int row = f >> 3, part = f & 7;    // row 0..127 chunk-local, 8 elems/thread
    const float4* yp = (const float4*)(Y + (jbase + row) * DDIM + part * 8);
    float4 u0 = yp[0], u1 = yp[1];
    float s = 0.f;
    s = fmaf(u0.x, u0.x, s); s = fmaf(u0.y, u0.y, s);
    s = fmaf(u0.z, u0.z, s); s = fmaf(u0.w, u0.w, s);
    s = fmaf(u1.x, u1.x, s); s = fmaf(u1.y, u1.y, s);
    s = fmaf(u1.z, u1.z, s); s = fmaf(u1.w, u1.w, s);
    bf16x8 hv = {(bf16_t)u0.x, (bf16_t)u0.y, (bf16_t)u0.z, (bf16_t)u0.w,
                 (bf16_t)u1.x, (bf16_t)u1.y, (bf16_t)u1.z, (bf16_t)u1.w};
    *(bf16x8*)&Ys[0][row * LSTR + part * 8] = hv;
    s += __shfl_xor(s, 1, 64);
    s += __shfl_xor(s, 2, 64);
    s += __shfl_xor(s, 4, 64);
    if (part == 0) y2L[0][row] = s;
  }
  __syncthreads();   // x2s, Ys[0], y2L[0] all ready

  // x2 values this lane needs (broadcast reads within 16-lane groups)
  float x2r[16];
#pragma unroll
  for (int a = 0; a < 4; ++a) {
    float4 v = *(const float4*)&x2s[rgb + a * 16 + q * 4];
    x2r[a * 4 + 0] = v.x; x2r[a * 4 + 1] = v.y;
    x2r[a * 4 + 2] = v.z; x2r[a * 4 + 3] = v.w;
  }

  float rmin[16];
#pragma unroll
  for (int k = 0; k < 16; ++k) rmin[k] = INFINITY;

  float4 Nst[8];   // next-chunk fp32 staging (32 VGPR)

  for (int cc = 0; cc < CHUNKS; ++cc) {
    const bf16_t* Yb = Ys[cc & 1];

    // y2 for this chunk from LDS
    float y2c[4];
#pragma unroll
    for (int b = 0; b < 4; ++b)
      y2c[b] = y2L[cc & 1][cgb + b * 16 + lr];

    // issue next chunk's fp32 loads now; latency hidden by MFMA compute
    if (cc + 1 < CHUNKS) {
      int j0n = jbase + (cc + 1) * 128;
#pragma unroll
      for (int p = 0; p < 4; ++p) {
        int f = p * 256 + tid;
        int row = f >> 3, part = f & 7;
        const float4* yp = (const float4*)(Y + (j0n + row) * DDIM + part * 8);
        Nst[p * 2] = yp[0];
        Nst[p * 2 + 1] = yp[1];
      }
    }

    // C init = x2_i + y2_j  (accumulator exits the MFMA pair as
    // d2 = x2 + y2 - 2<x,y> since A is pre-scaled by -2).
    // C/D layout: col = lr within 16, row = q*4+p.
    f32x4 acc[4][4];
#pragma unroll
    for (int a = 0; a < 4; ++a)
#pragma unroll
      for (int b = 0; b < 4; ++b) {
        acc[a][b][0] = x2r[a * 4 + 0] + y2c[b];
        acc[a][b][1] = x2r[a * 4 + 1] + y2c[b];
        acc[a][b][2] = x2r[a * 4 + 2] + y2c[b];
        acc[a][b][3] = x2r[a * 4 + 3] + y2c[b];
      }

#pragma unroll
    for (int b = 0; b < 4; ++b) {
      bf16x8 B0 = *(const bf16x8*)&Yb[(cgb + b * 16 + lr) * LSTR + q * 8];
      bf16x8 B1 = *(const bf16x8*)&Yb[(cgb + b * 16 + lr) * LSTR + 32 + q * 8];
#pragma unroll
      for (int a = 0; a < 4; ++a) {
        acc[a][b] = __builtin_amdgcn_mfma_f32_16x16x32_bf16(Af[a * 2 + 0], B0, acc[a][b], 0, 0, 0);
        acc[a][b] = __builtin_amdgcn_mfma_f32_16x16x32_bf16(Af[a * 2 + 1], B1, acc[a][b], 0, 0, 0);
      }
    }

    // ---- epilogue: acc IS d2; pure min3 trees ----
    float cmin[4] = {INFINITY, INFINITY, INFINITY, INFINITY};
#pragma unroll
    for (int a = 0; a < 4; ++a) {
#pragma unroll
      for (int p = 0; p < 4; ++p) {
        float rm = rmin[a * 4 + p];
        rm = fminf(fminf(rm, acc[a][0][p]), acc[a][1][p]);
        rmin[a * 4 + p] = fminf(fminf(rm, acc[a][2][p]), acc[a][3][p]);
      }
#pragma unroll
      for (int b = 0; b < 4; ++b) {
        float cm = cmin[b];
        cm = fminf(fminf(cm, acc[a][b][0]), acc[a][b][1]);
        cmin[b] = fminf(fminf(cm, acc[a][b][2]), acc[a][b][3]);
      }
    }
#pragma unroll
    for (int b = 0; b < 4; ++b) {
      cmin[b] = fminf(cmin[b], __shfl_xor(cmin[b], 16, 64));
      cmin[b] = fminf(cmin[b], __shfl_xor(cmin[b], 32, 64));
    }
    float v = cmin[0];
    if (q == 1) v = cmin[1];
    else if (q == 2) v = cmin[2];
    else if (q == 3) v = cmin[3];
    credL[cc & 1][rh][cgb + L] = v;   // col partial (full d2) for this row-half

    // ---- convert + write prefetched chunk into other buffer, one barrier ----
    if (cc + 1 < CHUNKS) {
      bf16_t* Yn = Ys[(cc + 1) & 1];
      float* y2n = y2L[(cc + 1) & 1];
#pragma unroll
      for (int p = 0; p < 4; ++p) {
        int f = p * 256 + tid;
        int row = f >> 3, part = f & 7;
        float4 u0 = Nst[p * 2], u1 = Nst[p * 2 + 1];
        float s = 0.f;
        s = fmaf(u0.x, u0.x, s); s = fmaf(u0.y, u0.y, s);
        s = fmaf(u0.z, u0.z, s); s = fmaf(u0.w, u0.w, s);
        s = fmaf(u1.x, u1.x, s); s = fmaf(u1.y, u1.y, s);
        s = fmaf(u1.z, u1.z, s); s = fmaf(u1.w, u1.w, s);
        bf16x8 hv = {(bf16_t)u0.x, (bf16_t)u0.y, (bf16_t)u0.z, (bf16_t)u0.w,
                     (bf16_t)u1.x, (bf16_t)u1.y, (bf16_t)u1.z, (bf16_t)u1.w};
        *(bf16x8*)&Yn[row * LSTR + part * 8] = hv;
        s += __shfl_xor(s, 1, 64);
        s += __shfl_xor(s, 2, 64);
        s += __shfl_xor(s, 4, 64);
        if (part == 0) y2n[row] = s;
      }
    }
    __syncthreads();

    // combine the two row-halves' col partials; each cslab slot written once.
    // credL[cc&1] is not rewritten until chunk cc+2's epilogue, which is
    // separated from this read by the barrier at the end of chunk cc+1.
    if (tid < 128) {
      float m = fminf(credL[cc & 1][0][tid], credL[cc & 1][1][tid]);
      cslab[itile * NROWS + jbase + cc * 128 + tid] = m;
    }
  }

  // ---- row mins (full d2): reduce across 16 col-lanes, [slice][row][ch] ----
#pragma unroll
  for (int a = 0; a < 4; ++a)
#pragma unroll
    for (int p = 0; p < 4; ++p) {
      float v = rmin[a * 4 + p];
      v = fminf(v, __shfl_xor(v, 1, 64));
      v = fminf(v, __shfl_xor(v, 2, 64));
      v = fminf(v, __shfl_xor(v, 4, 64));
      v = fminf(v, __shfl_xor(v, 8, 64));
      if (lr == 0)
        rslab[slice * (NROWS * 2) + (i0 + rgb + a * 16 + q * 4 + p) * 2 + ch] = v;
    }
}

// blocks [0,32): rows (256 rows each). blocks [32,160): cols (64 cols each,
// 4 thread-segments x 16 partials, LDS combine). Slabs carry full d2.
__global__ void finish_kernel(const float* __restrict__ rslab,
                              const float* __restrict__ cslab,
                              float* __restrict__ out) {
  const int b = blockIdx.x;
  const int tid = threadIdx.x;
  if (b < 32) {
    int row = b * 256 + tid;
    float m = INFINITY;
#pragma unroll
    for (int g = 0; g < SLICES; ++g) {
      float2 v = *(const float2*)&rslab[g * (NROWS * 2) + row * 2];
      m = fminf(m, fminf(v.x, v.y));
    }
    float v = sqrtf(fmaxf(m, 0.f)) * (1.0f / 8192.0f);
#pragma unroll
    for (int off = 32; off > 0; off >>= 1) v += __shfl_down(v, off, 64);
    __shared__ float partial[4];
    if ((tid & 63) == 0) partial[tid >> 6] = v;
    __syncthreads();
    if (tid == 0)
      atomicAdd(out, partial[0] + partial[1] + partial[2] + partial[3]);
  } else {
    int j = (b - 32) * 64 + (tid & 63);
    int seg = tid >> 6;
    float m = INFINITY;
#pragma unroll
    for (int k = 0; k < 16; ++k)
      m = fminf(m, cslab[(seg * 16 + k) * NROWS + j]);
    __shared__ float red[4][64];
    red[seg][tid & 63] = m;
    __syncthreads();
    if (tid < 64) {
      float mc = fminf(fminf(red[0][tid], red[1][tid]),
                       fminf(red[2][tid], red[3][tid]));
      float v = sqrtf(fmaxf(mc, 0.f)) * (1.0f / 8192.0f);
#pragma unroll
      for (int off = 32; off > 0; off >>= 1) v += __shfl_down(v, off, 64);
      if (tid == 0) atomicAdd(out, v);
    }
  }
}

extern "C" void kernel_launch(void* const* d_in, const int* in_sizes, int n_in,
                              void* d_out, int out_size, void* d_ws, size_t ws_size,
                              hipStream_t stream) {
  const float* X = (const float*)d_in[0];
  const float* Y = (const float*)d_in[1];
  float* out = (float*)d_out;

  char* wsb = (char*)d_ws;
  float* rslab = (float*)wsb;                   // [8][8192][2]  512 KB
  float* cslab = rslab + SLICES * NROWS * 2;    // [64][8192]    2 MB

  mine_kernel<<<ITILES * SLICES, 256, 0, stream>>>(X, Y, rslab, cslab, out);
  finish_kernel<<<160, 256, 0, stream>>>(rslab, cslab, out);
}